// Round 14
// baseline (503.331 us; speedup 1.0000x reference)
//
#include <hip/hip_runtime.h>
#include <hip/hip_bf16.h>
#include <hip/hip_fp16.h>

// ---------------------------------------------------------------------------
// GCN forward:  per layer  h' = ReLU( (Â h) @ W + b ),  aggregate-first.
// Node features stored fp16 PRE-SCALED by dis[i]:  hs[i] = dis[i]*h[i]
//   -> aggregation is a pure gather-SUM: a[i] = dis[i]*(hs[i] + sum hs[s])
// Aggregate: structural floor (~59.5us/256ch; FETCH = 8 XCD x |X| compulsory).
// R14: WEIGHT-STATIONARY GEMM. Whole W^T persisted in dynamic LDS (132 KB,
// stride 264 halves -> even 8-dword/bank b128 pattern), staged ONCE per
// block; grid-stride over 64-row M-tiles; A-fragments preloaded direct from
// global (coalesced 16-line wave loads, read exactly once, L2/L3-hot from
// the aggregate); K-loop has ZERO barriers. Grid = #CUs -> no tail.
// Layer-3 GEMM keeps fused mean-pool epilogue (batch read direct).
// ---------------------------------------------------------------------------

#define THREADS 256

typedef _Float16 f16x8 __attribute__((ext_vector_type(8)));
typedef float    f32x4 __attribute__((ext_vector_type(4)));

// ---------------- setup kernels ----------------

// degree histogram (i<E) + graph offsets from sorted batch (i<N), one launch
__global__ void degree_goff_kernel(const int* __restrict__ col, int* __restrict__ deg, int E,
                                   const int* __restrict__ batch, int* __restrict__ goff,
                                   int N, int G) {
    int i = blockIdx.x * THREADS + threadIdx.x;
    if (i < E) atomicAdd(&deg[col[i]], 1);
    if (i < N) {
        int b1 = batch[i];
        int b0 = (i == 0) ? -1 : batch[i - 1];
        for (int g = b0 + 1; g <= b1; ++g) goff[g] = i;
        if (i == N - 1) {
            for (int g = b1 + 1; g <= G; ++g) goff[g] = N;
        }
    }
}

// scan phase A: per-block (1024 elems) exclusive scan + block sum; also dis.
__global__ __launch_bounds__(256) void scanA_kernel(
    const int* __restrict__ in, int* __restrict__ out, int* __restrict__ bsum,
    float* __restrict__ dis, int n) {
    __shared__ int wsum[4];
    int i0 = blockIdx.x * 1024 + threadIdx.x * 4;
    int lane = threadIdx.x & 63, wid = threadIdx.x >> 6;
    int v0 = 0, v1 = 0, v2 = 0, v3 = 0;
    if (i0 + 3 < n) {
        int4 v = *(const int4*)&in[i0];
        v0 = v.x; v1 = v.y; v2 = v.z; v3 = v.w;
    } else {
        if (i0 + 0 < n) v0 = in[i0 + 0];
        if (i0 + 1 < n) v1 = in[i0 + 1];
        if (i0 + 2 < n) v2 = in[i0 + 2];
        if (i0 + 3 < n) v3 = in[i0 + 3];
    }
    // dis = rsqrt(deg+1) folded in (in == deg)
    if (i0 + 0 < n) dis[i0 + 0] = rsqrtf((float)(v0 + 1));
    if (i0 + 1 < n) dis[i0 + 1] = rsqrtf((float)(v1 + 1));
    if (i0 + 2 < n) dis[i0 + 2] = rsqrtf((float)(v2 + 1));
    if (i0 + 3 < n) dis[i0 + 3] = rsqrtf((float)(v3 + 1));
    int s = v0 + v1 + v2 + v3;
    int inc = s;
    #pragma unroll
    for (int d = 1; d < 64; d <<= 1) {
        int t = __shfl_up(inc, d);
        if (lane >= d) inc += t;
    }
    if (lane == 63) wsum[wid] = inc;
    __syncthreads();
    int add = 0;
    for (int w = 0; w < wid; ++w) add += wsum[w];
    int ex = add + inc - s;
    if (i0 + 0 < n) out[i0 + 0] = ex;
    if (i0 + 1 < n) out[i0 + 1] = ex + v0;
    if (i0 + 2 < n) out[i0 + 2] = ex + v0 + v1;
    if (i0 + 3 < n) out[i0 + 3] = ex + v0 + v1 + v2;
    if (threadIdx.x == 255) bsum[blockIdx.x] = add + inc;  // block total
}

// scan phase B: 1 wave scans <=64 block sums; writes grand total to out[n].
__global__ void scanB_kernel(int* __restrict__ bsum, int* __restrict__ total_slot, int nb) {
    int lane = threadIdx.x;
    int v = (lane < nb) ? bsum[lane] : 0;
    int inc = v;
    #pragma unroll
    for (int d = 1; d < 64; d <<= 1) {
        int t = __shfl_up(inc, d);
        if (lane >= d) inc += t;
    }
    if (lane < nb) bsum[lane] = inc - v;   // exclusive
    if (lane == 63) *total_slot = inc;
}

// uses deg as the countdown (deg no longer needed after scanA)
__global__ void csr_fill_kernel(const int* __restrict__ row, const int* __restrict__ col,
                                const int* __restrict__ offs, int* __restrict__ deg,
                                int* __restrict__ srcs, int E) {
    int e = blockIdx.x * THREADS + threadIdx.x;
    if (e < E) {
        int c = col[e];
        int old = atomicSub(&deg[c], 1);
        srcs[offs[c] + old - 1] = row[e];
    }
}

// merged: scanC (offs += bsum)  +  x fp32->fp16*dis  +  W1/W2/W3 -> fp16^T
__global__ void convert_kernel(
    int* __restrict__ offs, const int* __restrict__ bsum, int Nfix,
    const float* __restrict__ X, const float* __restrict__ dis,
    _Float16* __restrict__ Xs, int total8, int IC,
    const float* __restrict__ W1, _Float16* __restrict__ W1t, int k1,   // k1=IC
    const float* __restrict__ W2, _Float16* __restrict__ W2t,
    const float* __restrict__ W3, _Float16* __restrict__ W3t) {
    int i = blockIdx.x * THREADS + threadIdx.x;
    if (i < Nfix) {                         // scanC: add scanned block offsets
        offs[i] += bsum[i >> 10];
        return;
    }
    int j = i - Nfix;
    if (j < total8) {
        int idx = j * 8;
        float d = dis[idx / IC];
        float4 a = *(const float4*)&X[idx];
        float4 b = *(const float4*)&X[idx + 4];
        f16x8 o;
        o[0] = (_Float16)(d * a.x); o[1] = (_Float16)(d * a.y);
        o[2] = (_Float16)(d * a.z); o[3] = (_Float16)(d * a.w);
        o[4] = (_Float16)(d * b.x); o[5] = (_Float16)(d * b.y);
        o[6] = (_Float16)(d * b.z); o[7] = (_Float16)(d * b.w);
        *(f16x8*)&Xs[idx] = o;
        return;
    }
    j -= total8;
    int n1 = k1 * 256;
    if (j < n1) {                 // W1 [k1 x 256] -> W1t [256 x k1]
        int k = j >> 8, n = j & 255;
        W1t[n * k1 + k] = (_Float16)W1[j];
        return;
    }
    j -= n1;
    if (j < 65536) {              // W2 [256 x 256]
        int k = j >> 8, n = j & 255;
        W2t[n * 256 + k] = (_Float16)W2[j];
        return;
    }
    j -= 65536;
    if (j < 65536) {              // W3
        int k = j >> 8, n = j & 255;
        W3t[n * 256 + k] = (_Float16)W3[j];
    }
}

// ---- aggregation: a[i] = dis[i] * ( hs[i] + sum_{s in nbr} hs[s] ) ----------
// LPN lanes/node, 8 fp16 ch/lane, fp32 accumulate, 4-deep gather pipeline.
// (Structural floor: FETCH ~= 8 XCDs x |X| compulsory, ~3.7 TB/s miss path.)

template<int LPN>   // lanes per node = CH/8  (16 for 128ch, 32 for 256ch)
__global__ __launch_bounds__(256) void aggregate_f16_kernel(
    const _Float16* __restrict__ X, const int* __restrict__ offs,
    const int* __restrict__ srcs, const float* __restrict__ dis,
    _Float16* __restrict__ A, int N) {
    constexpr int NPB = 256 / LPN;
    int node = blockIdx.x * NPB + threadIdx.x / LPN;
    if (node >= N) return;
    int lane = threadIdx.x % LPN;
    const f16x8* Xv = (const f16x8*)X;
    f16x8 self = Xv[(size_t)node * LPN + lane];
    float acc[8], acc2[8];
    #pragma unroll
    for (int j = 0; j < 8; ++j) { acc[j] = (float)self[j]; acc2[j] = 0.f; }
    int s = offs[node], e = offs[node + 1];
    int i = s;
    for (; i + 4 <= e; i += 4) {
        int s0 = srcs[i], s1 = srcs[i + 1], s2 = srcs[i + 2], s3 = srcs[i + 3];
        f16x8 v0 = Xv[(size_t)s0 * LPN + lane];
        f16x8 v1 = Xv[(size_t)s1 * LPN + lane];
        f16x8 v2 = Xv[(size_t)s2 * LPN + lane];
        f16x8 v3 = Xv[(size_t)s3 * LPN + lane];
        #pragma unroll
        for (int j = 0; j < 8; ++j) {
            acc[j]  += (float)v0[j] + (float)v2[j];
            acc2[j] += (float)v1[j] + (float)v3[j];
        }
    }
    for (; i < e; ++i) {
        int s0 = srcs[i];
        f16x8 v0 = Xv[(size_t)s0 * LPN + lane];
        #pragma unroll
        for (int j = 0; j < 8; ++j) acc[j] += (float)v0[j];
    }
    float dn = dis[node];
    f16x8 o;
    #pragma unroll
    for (int j = 0; j < 8; ++j) o[j] = (_Float16)(dn * (acc[j] + acc2[j]));
    ((f16x8*)A)[(size_t)node * LPN + lane] = o;
}

// ---- WEIGHT-STATIONARY GEMM: H[m,:256] = relu(A[m,:K] @ W^T + b) -----------
// Dynamic LDS holds the whole W^T [256][K] (stride K+8: even bank spread).
// Grid-stride over 64-row M-tiles. Per tile: preload ALL A-fragments direct
// from global (each wave-load = 16 rows x 32 halves = 16 full lines), then a
// barrier-free K-loop: 4 LDS bh reads + 16 MFMAs per k-chunk.
// MODE 1: write H scaled by dscale[row]. MODE 2: fused mean-pool epilogue.

template<int K, int MODE>
__global__ __launch_bounds__(256) void gemm_ws_kernel(
    const _Float16* __restrict__ A, const _Float16* __restrict__ Bt,
    const float* __restrict__ bias, const float* __restrict__ dscale,
    _Float16* __restrict__ H, float* __restrict__ pooled,
    const int* __restrict__ batch, int M, int tiles) {
    extern __shared__ _Float16 Bs[];          // [256][LSB]
    constexpr int LSB = K + 8;
    constexpr int KC = K / 32;                // k-chunks
    int tid = threadIdx.x;

    // one-time stage of W^T (256 rows x K halves), 16B chunks
    constexpr int CHUNKS = 256 * K / 8;
    for (int idx = tid; idx < CHUNKS; idx += 256) {
        int r = idx / (K / 8), seg = idx % (K / 8);
        *(uint4*)&Bs[r * LSB + seg * 8] = *(const uint4*)&Bt[(size_t)r * K + seg * 8];
    }
    __syncthreads();

    int wid = tid >> 6, lane = tid & 63;
    int l16 = lane & 15, quad = lane >> 4;
    int wn = wid * 64;                        // this wave's 64 output cols

    for (int tile = blockIdx.x; tile < tiles; tile += gridDim.x) {
        int m0 = tile * 64;
        f32x4 acc[4][4] = {};
        // preload all A fragments for this tile (read exactly once, no LDS)
        f16x8 ahp[4][KC];
        #pragma unroll
        for (int mi = 0; mi < 4; ++mi) {
            size_t ar = (size_t)min(m0 + mi * 16 + l16, M - 1) * K + quad * 8;
            #pragma unroll
            for (int kc = 0; kc < KC; ++kc)
                ahp[mi][kc] = *(const f16x8*)&A[ar + kc * 32];
        }
        // barrier-free K loop
        #pragma unroll
        for (int kc = 0; kc < KC; ++kc) {
            f16x8 bh[4];
            #pragma unroll
            for (int ni = 0; ni < 4; ++ni)
                bh[ni] = *(const f16x8*)&Bs[(wn + ni * 16 + l16) * LSB + kc * 32 + quad * 8];
            #pragma unroll
            for (int mi = 0; mi < 4; ++mi) {
                #pragma unroll
                for (int ni = 0; ni < 4; ++ni)
                    acc[mi][ni] = __builtin_amdgcn_mfma_f32_16x16x32_f16(ahp[mi][kc], bh[ni], acc[mi][ni], 0, 0, 0);
            }
        }
        // epilogue
        #pragma unroll
        for (int mi = 0; mi < 4; ++mi) {
            int rbase = m0 + mi * 16;
            int g0 = 0, g15 = 0;
            if (MODE == 2) {
                g0  = batch[min(rbase, M - 1)];
                g15 = batch[min(rbase + 15, M - 1)];
            }
            #pragma unroll
            for (int ni = 0; ni < 4; ++ni) {
                int col = wn + ni * 16 + l16;
                float bv = bias[col];
                if (MODE == 1) {
                    #pragma unroll
                    for (int r = 0; r < 4; ++r) {
                        int grow = rbase + quad * 4 + r;
                        if (grow < M) {
                            float v = fmaxf(acc[mi][ni][r] + bv, 0.f) * dscale[grow];
                            H[(size_t)grow * 256 + col] = (_Float16)v;
                        }
                    }
                } else {  // MODE == 2: fused mean-pool accumulation
                    if (g0 == g15) {
                        float p = 0.f;
                        #pragma unroll
                        for (int r = 0; r < 4; ++r) {
                            int grow = rbase + quad * 4 + r;
                            float v = fmaxf(acc[mi][ni][r] + bv, 0.f);
                            p += (grow < M) ? v : 0.f;
                        }
                        p += __shfl_xor(p, 16);
                        p += __shfl_xor(p, 32);
                        if (quad == 0) atomicAdd(&pooled[g0 * 256 + col], p);
                    } else {
                        #pragma unroll
                        for (int r = 0; r < 4; ++r) {
                            int grow = rbase + quad * 4 + r;
                            if (grow < M) {
                                float v = fmaxf(acc[mi][ni][r] + bv, 0.f);
                                atomicAdd(&pooled[batch[grow] * 256 + col], v);
                            }
                        }
                    }
                }
            }
        }
    }
}

// ---------------- FFN: relu(pooled/cnt @Wf+bf) @ Wo + bo, one block/graph ----

__global__ __launch_bounds__(256) void ffn_kernel(
    const float* __restrict__ pooled, const int* __restrict__ goff,
    const float* __restrict__ Wf, const float* __restrict__ bf,
    const float* __restrict__ Wo, const float* __restrict__ bo,
    float* __restrict__ out) {
    __shared__ float p[256];
    __shared__ float red[256];
    int g = blockIdx.x, t = threadIdx.x;
    int cnt = goff[g + 1] - goff[g];
    float inv = 1.f / (float)max(cnt, 1);
    p[t] = pooled[g * 256 + t] * inv;
    __syncthreads();
    float s = bf[t];
    #pragma unroll 8
    for (int k = 0; k < 256; ++k) s = fmaf(p[k], Wf[k * 256 + t], s);
    float gv = fmaxf(s, 0.f);
    red[t] = gv * Wo[t];
    __syncthreads();
    for (int o = 128; o > 0; o >>= 1) {
        if (t < o) red[t] += red[t + o];
        __syncthreads();
    }
    if (t == 0) out[g] = red[0] + bo[0];
}

// ---------------------------------------------------------------------------

extern "C" void kernel_launch(void* const* d_in, const int* in_sizes, int n_in,
                              void* d_out, int out_size, void* d_ws, size_t ws_size,
                              hipStream_t stream) {
    const float* x   = (const float*)d_in[0];
    const int*   ei  = (const int*)d_in[1];
    const int*   bat = (const int*)d_in[2];
    const float* W1  = (const float*)d_in[3];
    const float* b1  = (const float*)d_in[4];
    const float* W2  = (const float*)d_in[5];
    const float* b2  = (const float*)d_in[6];
    const float* W3  = (const float*)d_in[7];
    const float* b3  = (const float*)d_in[8];
    const float* Wf  = (const float*)d_in[9];
    const float* bf  = (const float*)d_in[10];
    const float* Wo  = (const float*)d_in[11];
    const float* bo  = (const float*)d_in[12];
    float* out = (float*)d_out;

    const int N  = in_sizes[2];        // 50000
    const int E  = in_sizes[1] / 2;    // 800000
    const int IC = in_sizes[0] / N;    // 128
    const int HID = 256;
    const int G  = out_size;           // 256
    const int* row = ei;
    const int* col = ei + E;

    char* w = (char*)d_ws;
    size_t off = 0;
    auto alloc = [&](size_t bytes) -> void* {
        void* p = w + off;
        off += (bytes + 255) & ~(size_t)255;
        return p;
    };
    // deg and pooled adjacent -> one memset covers both
    int*   deg    = (int*)alloc((size_t)N * 4);
    float* pooled = (float*)alloc((size_t)G * HID * 4);
    float* dis    = (float*)alloc((size_t)N * 4);
    int*   offs   = (int*)alloc((size_t)(N + 1) * 4);
    int*   srcs   = (int*)alloc((size_t)E * 4);
    int*   goff   = (int*)alloc((size_t)(G + 1) * 4);
    int*   bsum   = (int*)alloc((size_t)64 * 4);
    _Float16* W1t = (_Float16*)alloc((size_t)HID * IC * 2);
    _Float16* W2t = (_Float16*)alloc((size_t)HID * HID * 2);
    _Float16* W3t = (_Float16*)alloc((size_t)HID * HID * 2);
    _Float16* Xs  = (_Float16*)alloc((size_t)N * IC * 2);
    _Float16* Ah  = (_Float16*)alloc((size_t)N * HID * 2);
    _Float16* Hs  = (_Float16*)alloc((size_t)N * HID * 2);
    (void)ws_size; (void)n_in;

    // opt in to >64KB dynamic LDS for the weight-stationary GEMMs (idempotent)
    size_t lds128 = (size_t)256 * (128 + 8) * 2;   // 69632
    size_t lds256 = (size_t)256 * (256 + 8) * 2;   // 135168
    (void)hipFuncSetAttribute((const void*)gemm_ws_kernel<128, 1>,
                              hipFuncAttributeMaxDynamicSharedMemorySize, (int)lds128);
    (void)hipFuncSetAttribute((const void*)gemm_ws_kernel<256, 1>,
                              hipFuncAttributeMaxDynamicSharedMemorySize, (int)lds256);
    (void)hipFuncSetAttribute((const void*)gemm_ws_kernel<256, 2>,
                              hipFuncAttributeMaxDynamicSharedMemorySize, (int)lds256);

    size_t zlen = (((size_t)N * 4 + 255) & ~(size_t)255) + (size_t)G * HID * 4;
    hipMemsetAsync(deg, 0, zlen, stream);

    int nb = (N + 1023) / 1024;   // 49 <= 64
    degree_goff_kernel<<<(E + THREADS - 1) / THREADS, THREADS, 0, stream>>>(
        col, deg, E, bat, goff, N, G);
    scanA_kernel<<<nb, 256, 0, stream>>>(deg, offs, bsum, dis, N);
    scanB_kernel<<<1, 64, 0, stream>>>(bsum, &offs[N], nb);

    int total8 = N * IC / 8;
    int conv_total = N + total8 + IC * HID + HID * HID + HID * HID;
    convert_kernel<<<(conv_total + THREADS - 1) / THREADS, THREADS, 0, stream>>>(
        offs, bsum, N, x, dis, Xs, total8, IC, W1, W1t, IC, W2, W2t, W3, W3t);

    csr_fill_kernel<<<(E + THREADS - 1) / THREADS, THREADS, 0, stream>>>(row, col, offs, deg, srcs, E);

    int tiles = (N + 63) / 64;   // 782
    // layer 1 (128 ch: 16 lanes/node); GEMM writes dis-scaled h1
    aggregate_f16_kernel<16><<<(N + 15) / 16, 256, 0, stream>>>(Xs, offs, srcs, dis, Ah, N);
    gemm_ws_kernel<128, 1><<<512, 256, lds128, stream>>>(Ah, W1t, b1, dis, Hs, nullptr, nullptr, N, tiles);
    // layer 2 (256 ch: 32 lanes/node); GEMM writes dis-scaled h2
    aggregate_f16_kernel<32><<<(N + 7) / 8, 256, 0, stream>>>(Hs, offs, srcs, dis, Ah, N);
    gemm_ws_kernel<256, 1><<<256, 256, lds256, stream>>>(Ah, W2t, b2, dis, Hs, nullptr, nullptr, N, tiles);
    // layer 3: GEMM fuses mean-pool (no H write)
    aggregate_f16_kernel<32><<<(N + 7) / 8, 256, 0, stream>>>(Hs, offs, srcs, dis, Ah, N);
    gemm_ws_kernel<256, 2><<<256, 256, lds256, stream>>>(Ah, W3t, b3, nullptr, nullptr, pooled, bat, N, tiles);

    ffn_kernel<<<G, 256, 0, stream>>>(pooled, goff, Wf, bf, Wo, bo, out);
}

// Round 15
// 425.206 us; speedup vs baseline: 1.1837x; 1.1837x over previous
//
#include <hip/hip_runtime.h>
#include <hip/hip_bf16.h>
#include <hip/hip_fp16.h>

// ---------------------------------------------------------------------------
// GCN forward:  per layer  h' = ReLU( (Â h) @ W + b ),  aggregate-first.
// Node features stored fp16 PRE-SCALED by dis[i]:  hs[i] = dis[i]*h[i]
//   -> aggregation is a pure gather-SUM: a[i] = dis[i]*(hs[i] + sum hs[s])
// Aggregate: structural floor (~59.5us/256ch; FETCH = 8 XCD x |X| compulsory).
// R15 GEMM: A-STATIONARY. 64-row A tile staged ONCE in LDS (stride K+40:
// S ≡ 40 mod 64 -> measured-conflict-free class), ONE barrier, then a
// barrier-free K-loop: per k-chunk 4 coalesced B-frag loads direct from
// global (B = 128KB, L2-hot, read once per wave) + 4 LDS A-reads + 16 MFMAs.
// No column split -> A read once from HBM. ~4 blocks/CU.
//   [R10 lesson: both operands global = L1 thrash. R14 lesson: 132KB LDS =
//    1 block/CU latency death. R12 lesson: stride class matters.]
// Layer-3 GEMM keeps fused mean-pool epilogue.
// ---------------------------------------------------------------------------

#define THREADS 256

typedef _Float16 f16x8 __attribute__((ext_vector_type(8)));
typedef float    f32x4 __attribute__((ext_vector_type(4)));

// ---------------- setup kernels ----------------

// degree histogram (i<E) + graph offsets from sorted batch (i<N), one launch
__global__ void degree_goff_kernel(const int* __restrict__ col, int* __restrict__ deg, int E,
                                   const int* __restrict__ batch, int* __restrict__ goff,
                                   int N, int G) {
    int i = blockIdx.x * THREADS + threadIdx.x;
    if (i < E) atomicAdd(&deg[col[i]], 1);
    if (i < N) {
        int b1 = batch[i];
        int b0 = (i == 0) ? -1 : batch[i - 1];
        for (int g = b0 + 1; g <= b1; ++g) goff[g] = i;
        if (i == N - 1) {
            for (int g = b1 + 1; g <= G; ++g) goff[g] = N;
        }
    }
}

// scan phase A: per-block (1024 elems) exclusive scan + block sum; also dis.
__global__ __launch_bounds__(256) void scanA_kernel(
    const int* __restrict__ in, int* __restrict__ out, int* __restrict__ bsum,
    float* __restrict__ dis, int n) {
    __shared__ int wsum[4];
    int i0 = blockIdx.x * 1024 + threadIdx.x * 4;
    int lane = threadIdx.x & 63, wid = threadIdx.x >> 6;
    int v0 = 0, v1 = 0, v2 = 0, v3 = 0;
    if (i0 + 3 < n) {
        int4 v = *(const int4*)&in[i0];
        v0 = v.x; v1 = v.y; v2 = v.z; v3 = v.w;
    } else {
        if (i0 + 0 < n) v0 = in[i0 + 0];
        if (i0 + 1 < n) v1 = in[i0 + 1];
        if (i0 + 2 < n) v2 = in[i0 + 2];
        if (i0 + 3 < n) v3 = in[i0 + 3];
    }
    // dis = rsqrt(deg+1) folded in (in == deg)
    if (i0 + 0 < n) dis[i0 + 0] = rsqrtf((float)(v0 + 1));
    if (i0 + 1 < n) dis[i0 + 1] = rsqrtf((float)(v1 + 1));
    if (i0 + 2 < n) dis[i0 + 2] = rsqrtf((float)(v2 + 1));
    if (i0 + 3 < n) dis[i0 + 3] = rsqrtf((float)(v3 + 1));
    int s = v0 + v1 + v2 + v3;
    int inc = s;
    #pragma unroll
    for (int d = 1; d < 64; d <<= 1) {
        int t = __shfl_up(inc, d);
        if (lane >= d) inc += t;
    }
    if (lane == 63) wsum[wid] = inc;
    __syncthreads();
    int add = 0;
    for (int w = 0; w < wid; ++w) add += wsum[w];
    int ex = add + inc - s;
    if (i0 + 0 < n) out[i0 + 0] = ex;
    if (i0 + 1 < n) out[i0 + 1] = ex + v0;
    if (i0 + 2 < n) out[i0 + 2] = ex + v0 + v1;
    if (i0 + 3 < n) out[i0 + 3] = ex + v0 + v1 + v2;
    if (threadIdx.x == 255) bsum[blockIdx.x] = add + inc;  // block total
}

// scan phase B: 1 wave scans <=64 block sums; writes grand total to out[n].
__global__ void scanB_kernel(int* __restrict__ bsum, int* __restrict__ total_slot, int nb) {
    int lane = threadIdx.x;
    int v = (lane < nb) ? bsum[lane] : 0;
    int inc = v;
    #pragma unroll
    for (int d = 1; d < 64; d <<= 1) {
        int t = __shfl_up(inc, d);
        if (lane >= d) inc += t;
    }
    if (lane < nb) bsum[lane] = inc - v;   // exclusive
    if (lane == 63) *total_slot = inc;
}

// uses deg as the countdown (deg no longer needed after scanA)
__global__ void csr_fill_kernel(const int* __restrict__ row, const int* __restrict__ col,
                                const int* __restrict__ offs, int* __restrict__ deg,
                                int* __restrict__ srcs, int E) {
    int e = blockIdx.x * THREADS + threadIdx.x;
    if (e < E) {
        int c = col[e];
        int old = atomicSub(&deg[c], 1);
        srcs[offs[c] + old - 1] = row[e];
    }
}

// merged: scanC (offs += bsum)  +  x fp32->fp16*dis  +  W1/W2/W3 -> fp16^T
__global__ void convert_kernel(
    int* __restrict__ offs, const int* __restrict__ bsum, int Nfix,
    const float* __restrict__ X, const float* __restrict__ dis,
    _Float16* __restrict__ Xs, int total8, int IC,
    const float* __restrict__ W1, _Float16* __restrict__ W1t, int k1,   // k1=IC
    const float* __restrict__ W2, _Float16* __restrict__ W2t,
    const float* __restrict__ W3, _Float16* __restrict__ W3t) {
    int i = blockIdx.x * THREADS + threadIdx.x;
    if (i < Nfix) {                         // scanC: add scanned block offsets
        offs[i] += bsum[i >> 10];
        return;
    }
    int j = i - Nfix;
    if (j < total8) {
        int idx = j * 8;
        float d = dis[idx / IC];
        float4 a = *(const float4*)&X[idx];
        float4 b = *(const float4*)&X[idx + 4];
        f16x8 o;
        o[0] = (_Float16)(d * a.x); o[1] = (_Float16)(d * a.y);
        o[2] = (_Float16)(d * a.z); o[3] = (_Float16)(d * a.w);
        o[4] = (_Float16)(d * b.x); o[5] = (_Float16)(d * b.y);
        o[6] = (_Float16)(d * b.z); o[7] = (_Float16)(d * b.w);
        *(f16x8*)&Xs[idx] = o;
        return;
    }
    j -= total8;
    int n1 = k1 * 256;
    if (j < n1) {                 // W1 [k1 x 256] -> W1t [256 x k1]
        int k = j >> 8, n = j & 255;
        W1t[n * k1 + k] = (_Float16)W1[j];
        return;
    }
    j -= n1;
    if (j < 65536) {              // W2 [256 x 256]
        int k = j >> 8, n = j & 255;
        W2t[n * 256 + k] = (_Float16)W2[j];
        return;
    }
    j -= 65536;
    if (j < 65536) {              // W3
        int k = j >> 8, n = j & 255;
        W3t[n * 256 + k] = (_Float16)W3[j];
    }
}

// ---- aggregation: a[i] = dis[i] * ( hs[i] + sum_{s in nbr} hs[s] ) ----------
// LPN lanes/node, 8 fp16 ch/lane, fp32 accumulate, 4-deep gather pipeline.
// (Structural floor: FETCH ~= 8 XCDs x |X| compulsory, ~3.7 TB/s miss path.)

template<int LPN>   // lanes per node = CH/8  (16 for 128ch, 32 for 256ch)
__global__ __launch_bounds__(256) void aggregate_f16_kernel(
    const _Float16* __restrict__ X, const int* __restrict__ offs,
    const int* __restrict__ srcs, const float* __restrict__ dis,
    _Float16* __restrict__ A, int N) {
    constexpr int NPB = 256 / LPN;
    int node = blockIdx.x * NPB + threadIdx.x / LPN;
    if (node >= N) return;
    int lane = threadIdx.x % LPN;
    const f16x8* Xv = (const f16x8*)X;
    f16x8 self = Xv[(size_t)node * LPN + lane];
    float acc[8], acc2[8];
    #pragma unroll
    for (int j = 0; j < 8; ++j) { acc[j] = (float)self[j]; acc2[j] = 0.f; }
    int s = offs[node], e = offs[node + 1];
    int i = s;
    for (; i + 4 <= e; i += 4) {
        int s0 = srcs[i], s1 = srcs[i + 1], s2 = srcs[i + 2], s3 = srcs[i + 3];
        f16x8 v0 = Xv[(size_t)s0 * LPN + lane];
        f16x8 v1 = Xv[(size_t)s1 * LPN + lane];
        f16x8 v2 = Xv[(size_t)s2 * LPN + lane];
        f16x8 v3 = Xv[(size_t)s3 * LPN + lane];
        #pragma unroll
        for (int j = 0; j < 8; ++j) {
            acc[j]  += (float)v0[j] + (float)v2[j];
            acc2[j] += (float)v1[j] + (float)v3[j];
        }
    }
    for (; i < e; ++i) {
        int s0 = srcs[i];
        f16x8 v0 = Xv[(size_t)s0 * LPN + lane];
        #pragma unroll
        for (int j = 0; j < 8; ++j) acc[j] += (float)v0[j];
    }
    float dn = dis[node];
    f16x8 o;
    #pragma unroll
    for (int j = 0; j < 8; ++j) o[j] = (_Float16)(dn * (acc[j] + acc2[j]));
    ((f16x8*)A)[(size_t)node * LPN + lane] = o;
}

// ---- A-STATIONARY GEMM: H[m,:256] = relu( A[m,:K] @ W^T + bias ) -----------
// 64-row tile per block. A staged once in LDS (stride K+40: conflict-free
// class), ONE barrier, then barrier-free K-loop: per kc each wave loads 4
// B-fragments direct from global (16 full lines each; B is L2-hot, read once
// per wave), 4 LDS A-frag reads, 16 MFMAs. Each of the 4 waves owns 64 cols.
// MODE 1: write H scaled by dscale[row]. MODE 2: fused mean-pool epilogue.

template<int K, int MODE>
__global__ __launch_bounds__(256) void gemm_as_kernel(
    const _Float16* __restrict__ A, const _Float16* __restrict__ Bt,
    const float* __restrict__ bias, const float* __restrict__ dscale,
    _Float16* __restrict__ H, float* __restrict__ pooled,
    const int* __restrict__ batch, int M) {
    constexpr int LSA = K + 40;               // ≡ 40 mod 64 -> even bank spread
    constexpr int KC = K / 32;
    constexpr int SPR = K / 8;                // 16B segs per row
    __shared__ _Float16 As[64 * LSA];
    int tid = threadIdx.x;
    int m0 = blockIdx.x * 64;

    // stage A tile once: rows-per-iter = 256/SPR; lane -> (row = t%RPI-group)
    {
        constexpr int RPI = 256 / SPR;        // 8 rows/iter (K=256), 16 (K=128)
        int r_in = tid % RPI;                 // consecutive lanes -> distinct rows
        int seg  = tid / RPI;                 //   => even LDS banks, 128B global runs
        #pragma unroll
        for (int it = 0; it < 64 / RPI; ++it) {
            int r = it * RPI + r_in;
            int gr = m0 + r;
            uint4 v = make_uint4(0, 0, 0, 0);
            if (gr < M) v = *(const uint4*)&A[(size_t)gr * K + seg * 8];
            *(uint4*)&As[r * LSA + seg * 8] = v;
        }
    }
    __syncthreads();

    int wid = tid >> 6, lane = tid & 63;
    int l16 = lane & 15, quad = lane >> 4;
    int wn = wid * 64;                        // this wave's 64 output cols

    f32x4 acc[4][4] = {};
    const _Float16* Bbase = Bt + (size_t)(wn + l16) * K + quad * 8;

    #pragma unroll
    for (int kc = 0; kc < KC; ++kc) {
        f16x8 bh[4];
        #pragma unroll
        for (int ni = 0; ni < 4; ++ni)
            bh[ni] = *(const f16x8*)&Bbase[(size_t)(ni * 16) * K + kc * 32];
        #pragma unroll
        for (int mi = 0; mi < 4; ++mi) {
            f16x8 ah = *(const f16x8*)&As[(mi * 16 + l16) * LSA + kc * 32 + quad * 8];
            #pragma unroll
            for (int ni = 0; ni < 4; ++ni)
                acc[mi][ni] = __builtin_amdgcn_mfma_f32_16x16x32_f16(ah, bh[ni], acc[mi][ni], 0, 0, 0);
        }
    }

    #pragma unroll
    for (int mi = 0; mi < 4; ++mi) {
        int rbase = m0 + mi * 16;
        int g0 = 0, g15 = 0;
        if (MODE == 2) {
            g0  = batch[min(rbase, M - 1)];
            g15 = batch[min(rbase + 15, M - 1)];
        }
        #pragma unroll
        for (int ni = 0; ni < 4; ++ni) {
            int col = wn + ni * 16 + l16;
            float bv = bias[col];
            if (MODE == 1) {
                #pragma unroll
                for (int r = 0; r < 4; ++r) {
                    int grow = rbase + quad * 4 + r;
                    if (grow < M) {
                        float v = fmaxf(acc[mi][ni][r] + bv, 0.f) * dscale[grow];
                        H[(size_t)grow * 256 + col] = (_Float16)v;
                    }
                }
            } else {  // MODE == 2: fused mean-pool accumulation
                if (g0 == g15) {
                    float p = 0.f;
                    #pragma unroll
                    for (int r = 0; r < 4; ++r) {
                        int grow = rbase + quad * 4 + r;
                        float v = fmaxf(acc[mi][ni][r] + bv, 0.f);
                        p += (grow < M) ? v : 0.f;
                    }
                    p += __shfl_xor(p, 16);
                    p += __shfl_xor(p, 32);
                    if (quad == 0) atomicAdd(&pooled[g0 * 256 + col], p);
                } else {
                    #pragma unroll
                    for (int r = 0; r < 4; ++r) {
                        int grow = rbase + quad * 4 + r;
                        if (grow < M) {
                            float v = fmaxf(acc[mi][ni][r] + bv, 0.f);
                            atomicAdd(&pooled[batch[grow] * 256 + col], v);
                        }
                    }
                }
            }
        }
    }
}

// ---------------- FFN: relu(pooled/cnt @Wf+bf) @ Wo + bo, one block/graph ----

__global__ __launch_bounds__(256) void ffn_kernel(
    const float* __restrict__ pooled, const int* __restrict__ goff,
    const float* __restrict__ Wf, const float* __restrict__ bf,
    const float* __restrict__ Wo, const float* __restrict__ bo,
    float* __restrict__ out) {
    __shared__ float p[256];
    __shared__ float red[256];
    int g = blockIdx.x, t = threadIdx.x;
    int cnt = goff[g + 1] - goff[g];
    float inv = 1.f / (float)max(cnt, 1);
    p[t] = pooled[g * 256 + t] * inv;
    __syncthreads();
    float s = bf[t];
    #pragma unroll 8
    for (int k = 0; k < 256; ++k) s = fmaf(p[k], Wf[k * 256 + t], s);
    float gv = fmaxf(s, 0.f);
    red[t] = gv * Wo[t];
    __syncthreads();
    for (int o = 128; o > 0; o >>= 1) {
        if (t < o) red[t] += red[t + o];
        __syncthreads();
    }
    if (t == 0) out[g] = red[0] + bo[0];
}

// ---------------------------------------------------------------------------

extern "C" void kernel_launch(void* const* d_in, const int* in_sizes, int n_in,
                              void* d_out, int out_size, void* d_ws, size_t ws_size,
                              hipStream_t stream) {
    const float* x   = (const float*)d_in[0];
    const int*   ei  = (const int*)d_in[1];
    const int*   bat = (const int*)d_in[2];
    const float* W1  = (const float*)d_in[3];
    const float* b1  = (const float*)d_in[4];
    const float* W2  = (const float*)d_in[5];
    const float* b2  = (const float*)d_in[6];
    const float* W3  = (const float*)d_in[7];
    const float* b3  = (const float*)d_in[8];
    const float* Wf  = (const float*)d_in[9];
    const float* bf  = (const float*)d_in[10];
    const float* Wo  = (const float*)d_in[11];
    const float* bo  = (const float*)d_in[12];
    float* out = (float*)d_out;

    const int N  = in_sizes[2];        // 50000
    const int E  = in_sizes[1] / 2;    // 800000
    const int IC = in_sizes[0] / N;    // 128
    const int HID = 256;
    const int G  = out_size;           // 256
    const int* row = ei;
    const int* col = ei + E;

    char* w = (char*)d_ws;
    size_t off = 0;
    auto alloc = [&](size_t bytes) -> void* {
        void* p = w + off;
        off += (bytes + 255) & ~(size_t)255;
        return p;
    };
    // deg and pooled adjacent -> one memset covers both
    int*   deg    = (int*)alloc((size_t)N * 4);
    float* pooled = (float*)alloc((size_t)G * HID * 4);
    float* dis    = (float*)alloc((size_t)N * 4);
    int*   offs   = (int*)alloc((size_t)(N + 1) * 4);
    int*   srcs   = (int*)alloc((size_t)E * 4);
    int*   goff   = (int*)alloc((size_t)(G + 1) * 4);
    int*   bsum   = (int*)alloc((size_t)64 * 4);
    _Float16* W1t = (_Float16*)alloc((size_t)HID * IC * 2);
    _Float16* W2t = (_Float16*)alloc((size_t)HID * HID * 2);
    _Float16* W3t = (_Float16*)alloc((size_t)HID * HID * 2);
    _Float16* Xs  = (_Float16*)alloc((size_t)N * IC * 2);
    _Float16* Ah  = (_Float16*)alloc((size_t)N * HID * 2);
    _Float16* Hs  = (_Float16*)alloc((size_t)N * HID * 2);
    (void)ws_size; (void)n_in;

    size_t zlen = (((size_t)N * 4 + 255) & ~(size_t)255) + (size_t)G * HID * 4;
    hipMemsetAsync(deg, 0, zlen, stream);

    int nb = (N + 1023) / 1024;   // 49 <= 64
    degree_goff_kernel<<<(E + THREADS - 1) / THREADS, THREADS, 0, stream>>>(
        col, deg, E, bat, goff, N, G);
    scanA_kernel<<<nb, 256, 0, stream>>>(deg, offs, bsum, dis, N);
    scanB_kernel<<<1, 64, 0, stream>>>(bsum, &offs[N], nb);

    int total8 = N * IC / 8;
    int conv_total = N + total8 + IC * HID + HID * HID + HID * HID;
    convert_kernel<<<(conv_total + THREADS - 1) / THREADS, THREADS, 0, stream>>>(
        offs, bsum, N, x, dis, Xs, total8, IC, W1, W1t, IC, W2, W2t, W3, W3t);

    csr_fill_kernel<<<(E + THREADS - 1) / THREADS, THREADS, 0, stream>>>(row, col, offs, deg, srcs, E);

    int mtiles = (N + 63) / 64;   // 782
    // layer 1 (128 ch: 16 lanes/node); GEMM writes dis-scaled h1
    aggregate_f16_kernel<16><<<(N + 15) / 16, 256, 0, stream>>>(Xs, offs, srcs, dis, Ah, N);
    gemm_as_kernel<128, 1><<<mtiles, 256, 0, stream>>>(Ah, W1t, b1, dis, Hs, nullptr, nullptr, N);
    // layer 2 (256 ch: 32 lanes/node); GEMM writes dis-scaled h2
    aggregate_f16_kernel<32><<<(N + 7) / 8, 256, 0, stream>>>(Hs, offs, srcs, dis, Ah, N);
    gemm_as_kernel<256, 1><<<mtiles, 256, 0, stream>>>(Ah, W2t, b2, dis, Hs, nullptr, nullptr, N);
    // layer 3: GEMM fuses mean-pool (no H write)
    aggregate_f16_kernel<32><<<(N + 7) / 8, 256, 0, stream>>>(Hs, offs, srcs, dis, Ah, N);
    gemm_as_kernel<256, 2><<<mtiles, 256, 0, stream>>>(Ah, W3t, b3, nullptr, nullptr, pooled, bat, N);

    ffn_kernel<<<G, 256, 0, stream>>>(pooled, goff, Wf, bf, Wo, bo, out);
}